// Round 2
// baseline (96.373 us; speedup 1.0000x reference)
//
#include <hip/hip_runtime.h>

// ClassCaps vote transform:
//   votes[b,h,w,i,o,m,p] = sum_n poses[b,h,w,i,m,n] * weight[i,o,n,p]
//                          + (m==0&&p==3 ? xv[h,w] : 0) + (m==1&&p==3 ? yv[h,w] : 0)
// Outputs (concatenated in d_out): votes [B*H*W*CIN*COUT*16] fp32, acts [B*H*W*CIN] fp32.
//
// One thread = one full 4x4 vote matrix (site, o). Index math once per thread,
// weight read directly through L1 (20 KB, resident), no LDS, no loop.

namespace {
constexpr int kB = 64, kH = 14, kW = 14, kCIN = 32, kCOUT = 10;
constexpr int kHW = kH * kW;                       // 196
constexpr int kSITES = kB * kH * kW * kCIN;        // 401408  (b,h,w,i) sites
constexpr int kMATS = kSITES * kCOUT;              // 4,014,080 vote matrices
constexpr int kVotesFloats = kMATS * 16;           // 64,225,280 floats
constexpr int kMatBlocks = kMATS / 256;            // 15680 (exact)
constexpr int kActsF4 = kSITES / 4;                // 100352 float4s
constexpr int kActBlocks = (kActsF4 + 255) / 256;  // 392
}

__device__ __forceinline__ float4 mat_row(const float4 p, const float4 w0,
                                          const float4 w1, const float4 w2,
                                          const float4 w3) {
    float4 r;
    r.x = fmaf(p.x, w0.x, fmaf(p.y, w1.x, fmaf(p.z, w2.x, p.w * w3.x)));
    r.y = fmaf(p.x, w0.y, fmaf(p.y, w1.y, fmaf(p.z, w2.y, p.w * w3.y)));
    r.z = fmaf(p.x, w0.z, fmaf(p.y, w1.z, fmaf(p.z, w2.z, p.w * w3.z)));
    r.w = fmaf(p.x, w0.w, fmaf(p.y, w1.w, fmaf(p.z, w2.w, p.w * w3.w)));
    return r;
}

__global__ __launch_bounds__(256) void classcaps_kernel(
    const float4* __restrict__ poses,    // [kSITES*4] float4 (row m of site)
    const float4* __restrict__ acts4,    // [kSITES/4]
    const float4* __restrict__ weight4,  // [kCIN*kCOUT*4] float4 (row n of (i,o))
    const float*  __restrict__ xv,       // [196]
    const float*  __restrict__ yv,       // [196]
    float4*       __restrict__ out_votes,
    float4*       __restrict__ out_acts)
{
    const int blk = blockIdx.x;
    if (blk >= kMatBlocks) {
        // activations pass-through
        const int t = (blk - kMatBlocks) * 256 + threadIdx.x;
        if (t < kActsF4) out_acts[t] = acts4[t];
        return;
    }

    const int so   = blk * 256 + threadIdx.x;   // site*10 + o
    const int site = so / 10;
    const int o    = so - site * 10;
    const int i    = site & (kCIN - 1);
    const int hw   = (site >> 5) % kHW;         // site>>5 = b*196 + hw

    const float4* pr = poses + site * 4;
    const float4 p0 = pr[0], p1 = pr[1], p2 = pr[2], p3 = pr[3];

    const float4* wr = weight4 + (i * kCOUT + o) * 4;
    const float4 w0 = wr[0], w1 = wr[1], w2 = wr[2], w3 = wr[3];

    float4 r0 = mat_row(p0, w0, w1, w2, w3);
    float4 r1 = mat_row(p1, w0, w1, w2, w3);
    float4 r2 = mat_row(p2, w0, w1, w2, w3);
    float4 r3 = mat_row(p3, w0, w1, w2, w3);

    r0.w += xv[hw];
    r1.w += yv[hw];

    float4* out = out_votes + so * 4;
    out[0] = r0;
    out[1] = r1;
    out[2] = r2;
    out[3] = r3;
}

extern "C" void kernel_launch(void* const* d_in, const int* in_sizes, int n_in,
                              void* d_out, int out_size, void* d_ws, size_t ws_size,
                              hipStream_t stream) {
    const float4* poses   = (const float4*)d_in[0];
    const float4* acts4   = (const float4*)d_in[1];
    const float4* weight4 = (const float4*)d_in[2];
    const float*  xv      = (const float*)d_in[3];
    const float*  yv      = (const float*)d_in[4];

    float* out = (float*)d_out;
    float4* out_votes = (float4*)out;
    float4* out_acts  = (float4*)(out + kVotesFloats);

    dim3 grid(kMatBlocks + kActBlocks), block(256);
    classcaps_kernel<<<grid, block, 0, stream>>>(
        poses, acts4, weight4, xv, yv, out_votes, out_acts);
}

// Round 3
// 72.636 us; speedup vs baseline: 1.3268x; 1.3268x over previous
//
#include <hip/hip_runtime.h>

// ClassCaps vote transform:
//   votes[b,h,w,i,o,m,p] = sum_n poses[b,h,w,i,m,n] * weight[i,o,n,p]
//                          + (m==0&&p==3 ? xv[h,w] : 0) + (m==1&&p==3 ? yv[h,w] : 0)
// Outputs (concatenated): votes [B*H*W*CIN*COUT*16] fp32, acts [B*H*W*CIN] fp32.
//
// Grid-stride over output float4s with stride % 1280 == 0, so each thread's
// (i, o, m) is FIXED: its 16 weight floats live in registers for the whole
// kernel. Per iteration: 1 pose float4 load (software-pipelined one iter
// ahead), 16 FMA, 1 lane-contiguous float4 store. No LDS.

namespace {
constexpr int kCIN = 32, kCOUT = 10, kHW = 14 * 14;
constexpr int kSITES = 64 * kHW * kCIN;            // 401408
constexpr int kVotesF4 = kSITES * kCOUT * 4;       // 16,056,320 float4s
constexpr int kVotesFloats = kVotesF4 * 4;
constexpr int kMatBlocks = 2050;                   // 2050*256 = 524800 = 1280*410
constexpr int kThreads = kMatBlocks * 256;         // f4-stride, %1280 == 0
constexpr int kSiteStep = kThreads / (kCOUT * 4);  // 13120, %32 == 0 -> i fixed
constexpr int kActsF4 = kSITES / 4;                // 100352
constexpr int kActBlocks = (kActsF4 + 255) / 256;  // 392
}

__global__ __launch_bounds__(256) void classcaps_kernel(
    const float4* __restrict__ poses,    // [kSITES*4]: row m of site at site*4+m
    const float4* __restrict__ acts4,    // [kSITES/4]
    const float4* __restrict__ weight4,  // [kCIN*kCOUT*4]: row n of (i,o)
    const float*  __restrict__ xv,       // [196]
    const float*  __restrict__ yv,       // [196]
    float4*       __restrict__ out_votes,
    float4*       __restrict__ out_acts)
{
    const int blk = blockIdx.x;
    if (blk >= kMatBlocks) {
        const int t = (blk - kMatBlocks) * 256 + threadIdx.x;
        if (t < kActsF4) out_acts[t] = acts4[t];
        return;
    }

    const int tid = blk * 256 + threadIdx.x;
    // Decode once: fixed for this thread across all iterations.
    const int m    = tid & 3;
    const int so   = tid >> 2;
    const int site0 = so / kCOUT;
    const int o    = so - site0 * kCOUT;
    const int i    = site0 & (kCIN - 1);

    // Weight matrix for (i,o): 16 floats in registers, loaded once.
    const float4* wr = weight4 + (i * kCOUT + o) * 4;
    const float4 w0 = wr[0], w1 = wr[1], w2 = wr[2], w3 = wr[3];

    int f    = tid;
    int site = site0;
    float4 p = poses[site * 4 + m];                 // prefetch iter 0

    while (f < kVotesF4) {
        const int f_next    = f + kThreads;
        const int site_next = site + kSiteStep;
        float4 p_next;
        const bool more = (f_next < kVotesF4);
        if (more) p_next = poses[site_next * 4 + m];  // prefetch iter k+1

        float4 r;
        r.x = fmaf(p.x, w0.x, fmaf(p.y, w1.x, fmaf(p.z, w2.x, p.w * w3.x)));
        r.y = fmaf(p.x, w0.y, fmaf(p.y, w1.y, fmaf(p.z, w2.y, p.w * w3.y)));
        r.z = fmaf(p.x, w0.z, fmaf(p.y, w1.z, fmaf(p.z, w2.z, p.w * w3.z)));
        r.w = fmaf(p.x, w0.w, fmaf(p.y, w1.w, fmaf(p.z, w2.w, p.w * w3.w)));

        if (m == 0) {
            const int bhw = site >> 5;               // b*196 + hw
            r.w += xv[bhw % kHW];
        } else if (m == 1) {
            const int bhw = site >> 5;
            r.w += yv[bhw % kHW];
        }

        out_votes[f] = r;                            // lane-contiguous float4

        f = f_next; site = site_next; p = p_next;
    }
}

extern "C" void kernel_launch(void* const* d_in, const int* in_sizes, int n_in,
                              void* d_out, int out_size, void* d_ws, size_t ws_size,
                              hipStream_t stream) {
    const float4* poses   = (const float4*)d_in[0];
    const float4* acts4   = (const float4*)d_in[1];
    const float4* weight4 = (const float4*)d_in[2];
    const float*  xv      = (const float*)d_in[3];
    const float*  yv      = (const float*)d_in[4];

    float* out = (float*)d_out;
    float4* out_votes = (float4*)out;
    float4* out_acts  = (float4*)(out + kVotesFloats);

    dim3 grid(kMatBlocks + kActBlocks), block(256);
    classcaps_kernel<<<grid, block, 0, stream>>>(
        poses, acts4, weight4, xv, yv, out_votes, out_acts);
}

// Round 4
// 63.483 us; speedup vs baseline: 1.5181x; 1.1442x over previous
//
#include <hip/hip_runtime.h>

// ClassCaps vote transform:
//   votes[b,h,w,i,o,m,p] = sum_n poses[b,h,w,i,m,n] * weight[i,o,n,p]
//                          + (m==0&&p==3 ? xv[h,w] : 0) + (m==1&&p==3 ? yv[h,w] : 0)
// Outputs (concatenated): votes [B*H*W*CIN*COUT*16] fp32, acts [B*H*W*CIN] fp32.
//
// Grid-stride chosen so each thread's (i, o, m, hw) are ALL loop-invariant:
//   f4-stride = 501760 -> site-step = 12544; 12544%32==0 (i fixed),
//   (12544>>5)%196==0 (hw fixed). Weights (16 floats) and the coord scalar
//   live in registers; inner loop = 1 f4 load + 16 FMA + 1 add + 1 f4 store,
//   branchless, exact 32-iteration trip, 2-deep prefetch.

namespace {
constexpr int kCIN = 32, kCOUT = 10, kHW = 14 * 14;
constexpr int kSITES = 64 * kHW * kCIN;            // 401408
constexpr int kVotesF4 = kSITES * kCOUT * 4;       // 16,056,320 float4s
constexpr int kVotesFloats = kVotesF4 * 4;
constexpr int kVoteBlocks = 1960;
constexpr int kThreads = kVoteBlocks * 256;        // 501760 = f4 grid stride
constexpr int kSiteStep = kThreads / (kCOUT * 4);  // 12544 sites per iter
constexpr int kPStep = kSiteStep * 4;              // pose float4s per iter
constexpr int kIters = kVotesF4 / kThreads;        // 32 (exact)
constexpr int kActsF4 = kSITES / 4;                // 100352
constexpr int kActBlocks = kActsF4 / 256;          // 392 (exact)
}

__device__ __forceinline__ float4 vote_row(const float4 p, const float4 w0,
                                           const float4 w1, const float4 w2,
                                           const float4 w3, const float cx) {
    float4 r;
    r.x = fmaf(p.x, w0.x, fmaf(p.y, w1.x, fmaf(p.z, w2.x, p.w * w3.x)));
    r.y = fmaf(p.x, w0.y, fmaf(p.y, w1.y, fmaf(p.z, w2.y, p.w * w3.y)));
    r.z = fmaf(p.x, w0.z, fmaf(p.y, w1.z, fmaf(p.z, w2.z, p.w * w3.z)));
    r.w = fmaf(p.x, w0.w, fmaf(p.y, w1.w, fmaf(p.z, w2.w, p.w * w3.w))) + cx;
    return r;
}

__global__ __launch_bounds__(256) void classcaps_kernel(
    const float4* __restrict__ poses,    // [kSITES*4]: row m of site at site*4+m
    const float4* __restrict__ acts4,    // [kSITES/4]
    const float4* __restrict__ weight4,  // [kCIN*kCOUT*4]: row n of (i,o)
    const float*  __restrict__ xv,       // [196]
    const float*  __restrict__ yv,       // [196]
    float4*       __restrict__ out_votes,
    float4*       __restrict__ out_acts)
{
    const int blk = blockIdx.x;
    if (blk >= kVoteBlocks) {
        const int t = (blk - kVoteBlocks) * 256 + threadIdx.x;
        out_acts[t] = acts4[t];   // exact coverage, no bounds check
        return;
    }

    const int tid   = blk * 256 + threadIdx.x;
    const int m     = tid & 3;
    const int so    = tid >> 2;
    const int site0 = so / kCOUT;
    const int o     = so - site0 * kCOUT;
    const int i     = site0 & (kCIN - 1);
    const int hw    = (site0 >> 5) % kHW;          // loop-invariant

    // Branchless coord scalar, loaded once.
    const float cx = (m == 0) ? xv[hw] : (m == 1) ? yv[hw] : 0.0f;

    // Weight matrix for (i,o): 16 floats in registers, loaded once.
    const float4* wr = weight4 + (i * kCOUT + o) * 4;
    const float4 w0 = wr[0], w1 = wr[1], w2 = wr[2], w3 = wr[3];

    const float4* pp = poses + site0 * 4 + m;
    float4*       op = out_votes + tid;

    // 2-deep software pipeline, exact trip count.
    float4 pa = pp[0];
    float4 pb = pp[kPStep];
    pp += 2 * kPStep;

    #pragma unroll 2
    for (int k = 0; k < kIters - 2; ++k) {
        const float4 cur = pa;
        pa = pb;
        pb = pp[0];                 // prefetch iter k+2
        pp += kPStep;
        *op = vote_row(cur, w0, w1, w2, w3, cx);
        op += kThreads;
    }
    *op = vote_row(pa, w0, w1, w2, w3, cx);
    op += kThreads;
    *op = vote_row(pb, w0, w1, w2, w3, cx);
}

extern "C" void kernel_launch(void* const* d_in, const int* in_sizes, int n_in,
                              void* d_out, int out_size, void* d_ws, size_t ws_size,
                              hipStream_t stream) {
    const float4* poses   = (const float4*)d_in[0];
    const float4* acts4   = (const float4*)d_in[1];
    const float4* weight4 = (const float4*)d_in[2];
    const float*  xv      = (const float*)d_in[3];
    const float*  yv      = (const float*)d_in[4];

    float* out = (float*)d_out;
    float4* out_votes = (float4*)out;
    float4* out_acts  = (float4*)(out + kVotesFloats);

    dim3 grid(kVoteBlocks + kActBlocks), block(256);
    classcaps_kernel<<<grid, block, 0, stream>>>(
        poses, acts4, weight4, xv, yv, out_votes, out_acts);
}

// Round 5
// 61.097 us; speedup vs baseline: 1.5774x; 1.0390x over previous
//
#include <hip/hip_runtime.h>

// ClassCaps vote transform:
//   votes[b,h,w,i,o,m,p] = sum_n poses[b,h,w,i,m,n] * weight[i,o,n,p]
//                          + (m==0&&p==3 ? xv[h,w] : 0) + (m==1&&p==3 ? yv[h,w] : 0)
// Outputs (concatenated): votes [B*H*W*CIN*COUT*16] fp32, acts [B*H*W*CIN] fp32.
//
// Grid = 1280 blocks exactly = 5 blocks/CU on 256 CUs: ALL blocks co-resident,
// no dispatch tail, perfect balance. f4-stride = 327680 -> site-step = 8192:
// (i, o, m) loop-invariant (weights in registers); hw advances by +60 mod 196
// per iteration (incremental, branchless coord gather from L1). Trip count
// exactly 49. Acts copy folded into blocks 0..391 (exact coverage).

namespace {
constexpr int kCIN = 32, kCOUT = 10, kHW = 14 * 14;
constexpr int kSITES = 64 * kHW * kCIN;            // 401408
constexpr int kVotesF4 = kSITES * kCOUT * 4;       // 16,056,320 float4s
constexpr int kVotesFloats = kVotesF4 * 4;
constexpr int kVoteBlocks = 1280;                  // 5 blocks/CU exactly
constexpr int kThreads = kVoteBlocks * 256;        // 327,680 = f4 grid stride
constexpr int kSiteStep = kThreads / (kCOUT * 4);  // 8192 sites per iter
constexpr int kPStep = kSiteStep * 4;              // pose float4s per iter
constexpr int kHwStep = (kSiteStep >> 5) % kHW;    // 60
constexpr int kIters = kVotesF4 / kThreads;        // 49 (exact)
constexpr int kActsF4 = kSITES / 4;                // 100352 = 392 * 256
constexpr int kActBlocks = kActsF4 / 256;          // 392
}

__device__ __forceinline__ float4 vote_row(const float4 p, const float4 w0,
                                           const float4 w1, const float4 w2,
                                           const float4 w3, const float cx) {
    float4 r;
    r.x = fmaf(p.x, w0.x, fmaf(p.y, w1.x, fmaf(p.z, w2.x, p.w * w3.x)));
    r.y = fmaf(p.x, w0.y, fmaf(p.y, w1.y, fmaf(p.z, w2.y, p.w * w3.y)));
    r.z = fmaf(p.x, w0.z, fmaf(p.y, w1.z, fmaf(p.z, w2.z, p.w * w3.z)));
    r.w = fmaf(p.x, w0.w, fmaf(p.y, w1.w, fmaf(p.z, w2.w, p.w * w3.w))) + cx;
    return r;
}

__global__ __launch_bounds__(256) void classcaps_kernel(
    const float4* __restrict__ poses,    // [kSITES*4]: row m of site at site*4+m
    const float4* __restrict__ acts4,    // [kSITES/4]
    const float4* __restrict__ weight4,  // [kCIN*kCOUT*4]: row n of (i,o)
    const float*  __restrict__ xv,       // [196]
    const float*  __restrict__ yv,       // [196]
    float4*       __restrict__ out_votes,
    float4*       __restrict__ out_acts)
{
    const int blk = blockIdx.x;
    const int tid = blk * 256 + threadIdx.x;

    // Activations pass-through, folded into the first 392 blocks (exact).
    if (blk < kActBlocks) out_acts[tid] = acts4[tid];

    const int m     = tid & 3;
    const int so    = tid >> 2;
    const int site0 = so / kCOUT;
    const int o     = so - site0 * kCOUT;
    const int i     = site0 & (kCIN - 1);
    int hw          = (site0 >> 5) % kHW;

    // Branchless coord source: m=0 -> xv, m=1 -> yv, m>=2 -> *0.
    const float* ctab = (m & 1) ? yv : xv;
    const float cmask = (m < 2) ? 1.0f : 0.0f;

    // Weight matrix for (i,o): 16 floats in registers, loaded once.
    const float4* wr = weight4 + (i * kCOUT + o) * 4;
    const float4 w0 = wr[0], w1 = wr[1], w2 = wr[2], w3 = wr[3];

    const float4* pp = poses + site0 * 4 + m;
    float4*       op = out_votes + tid;

    // 2-deep software pipeline, exact 49-iteration trip.
    float4 pa = pp[0];
    float4 pb = pp[kPStep];
    pp += 2 * kPStep;
    float cx = ctab[hw] * cmask;                 // coord for iter 0

    #pragma unroll 2
    for (int k = 0; k < kIters - 2; ++k) {
        const float4 cur = pa;
        pa = pb;
        pb = pp[0];                              // prefetch iter k+2
        pp += kPStep;
        const float c_cur = cx;                  // coord for iter k
        hw += kHwStep; if (hw >= kHW) hw -= kHW; // advance to iter k+1
        cx = ctab[hw] * cmask;
        *op = vote_row(cur, w0, w1, w2, w3, c_cur);
        op += kThreads;
    }
    // Epilogue: iterations 47 and 48.
    const float c0 = cx;
    hw += kHwStep; if (hw >= kHW) hw -= kHW;
    const float c1 = ctab[hw] * cmask;
    *op = vote_row(pa, w0, w1, w2, w3, c0);
    op += kThreads;
    *op = vote_row(pb, w0, w1, w2, w3, c1);
}

extern "C" void kernel_launch(void* const* d_in, const int* in_sizes, int n_in,
                              void* d_out, int out_size, void* d_ws, size_t ws_size,
                              hipStream_t stream) {
    const float4* poses   = (const float4*)d_in[0];
    const float4* acts4   = (const float4*)d_in[1];
    const float4* weight4 = (const float4*)d_in[2];
    const float*  xv      = (const float*)d_in[3];
    const float*  yv      = (const float*)d_in[4];

    float* out = (float*)d_out;
    float4* out_votes = (float4*)out;
    float4* out_acts  = (float4*)(out + kVotesFloats);

    dim3 grid(kVoteBlocks), block(256);
    classcaps_kernel<<<grid, block, 0, stream>>>(
        poses, acts4, weight4, xv, yv, out_votes, out_acts);
}